// Round 1
// baseline (740.383 us; speedup 1.0000x reference)
//
#include <hip/hip_runtime.h>

#define NNODES 21844
#define ENC 256
#define HID 1024
#define ROWS 4096   // B*S = 128*32
#define NTIMES 48

typedef __attribute__((ext_vector_type(8))) short bf16x8;
typedef __attribute__((ext_vector_type(4))) float f32x4;

__device__ inline unsigned short f2bf(float f) {
  unsigned int u = __float_as_uint(f);
  u += 0x7FFF + ((u >> 16) & 1);   // round-to-nearest-even
  return (unsigned short)(u >> 16);
}

// map global score column -> (depth block size, output base index for row 0)
__device__ inline void col_map(int c, int& nd, int& obase) {
  int off;
  if (c < 340) {
    if (c < 20)  { if (c < 4)   { off = 0;   nd = 4;   } else { off = 4;    nd = 16;   } }
    else         { if (c < 84)  { off = 20;  nd = 64;  } else { off = 84;   nd = 256;  } }
  } else {
    if (c < 5460){ if (c < 1364){ off = 340; nd = 1024;} else { off = 1364; nd = 4096; } }
    else         { off = 5460; nd = 16384; }
  }
  obase = ROWS * off + (c - off);
}

// ---------------- fp32 -> bf16 conversion (vectorized) ----------------
__global__ __launch_bounds__(256) void conv_bf16(const float* __restrict__ in,
                                                 unsigned short* __restrict__ out, int n4) {
  int i = blockIdx.x * 256 + threadIdx.x;
  if (i >= n4) return;
  float4 v = reinterpret_cast<const float4*>(in)[i];
  ushort4 o;
  o.x = f2bf(v.x); o.y = f2bf(v.y); o.z = f2bf(v.z); o.w = f2bf(v.w);
  reinterpret_cast<ushort4*>(out)[i] = o;
}

// ---------------- W_key [1024,256] -> bf16 transposed [256,1024] ----------------
__global__ __launch_bounds__(256) void wk_transpose(const float* __restrict__ Wk,
                                                    unsigned short* __restrict__ WkT) {
  int i = blockIdx.x * 256 + threadIdx.x;     // 262144 total
  int e = i >> 10, h = i & 1023;
  WkT[i] = f2bf(Wk[h * ENC + e]);
}

// ---------------- W_time [48,1024] -> fp32 transposed [1024,48] ----------------
__global__ __launch_bounds__(256) void wt_transpose(const float* __restrict__ Wt,
                                                    float* __restrict__ WtT) {
  int i = blockIdx.x * 256 + threadIdx.x;     // 49152 total
  if (i >= NTIMES * HID) return;
  int k = i / NTIMES, c = i % NTIMES;
  WtT[i] = Wt[c * HID + k];
}

// ---------------- pb[r] = prefix[r,:] . b_key ----------------
__global__ __launch_bounds__(256) void pb_kernel(const float* __restrict__ prefix,
                                                 const float* __restrict__ bk,
                                                 float* __restrict__ pb) {
  int lane = threadIdx.x & 63;
  int r = blockIdx.x * 4 + (threadIdx.x >> 6);
  const float4* pr = reinterpret_cast<const float4*>(prefix + (long)r * HID);
  const float4* bv = reinterpret_cast<const float4*>(bk);
  float s = 0.f;
#pragma unroll
  for (int i = 0; i < 4; ++i) {
    float4 a = pr[lane + 64 * i], b = bv[lane + 64 * i];
    s += a.x * b.x + a.y * b.y + a.z * b.z + a.w * b.w;
  }
#pragma unroll
  for (int d = 32; d; d >>= 1) s += __shfl_xor(s, d);
  if (lane == 0) pb[r] = s;
}

// ---------------- P2 = prefix @ W_key  (bf16 MFMA, K=1024) -> bf16 [4096,256] ----------------
__global__ __launch_bounds__(256) void p2_mfma(const unsigned short* __restrict__ Ab,   // prefix bf16 [4096,1024]
                                               const unsigned short* __restrict__ Bb,   // W_key^T bf16 [256,1024]
                                               unsigned short* __restrict__ P2) {
  int lane = threadIdx.x & 63, w = threadIdx.x >> 6;
  int lr = lane & 15, lg = lane >> 4;
  int m0 = blockIdx.x * 64 + w * 16;
  f32x4 acc[16];
#pragma unroll
  for (int nt = 0; nt < 16; ++nt) acc[nt] = f32x4{0.f, 0.f, 0.f, 0.f};
  const unsigned short* Ap = Ab + (m0 + lr) * HID + lg * 8;
  for (int kk = 0; kk < 32; ++kk) {
    bf16x8 a = *reinterpret_cast<const bf16x8*>(Ap + kk * 32);
#pragma unroll
    for (int nt = 0; nt < 16; ++nt) {
      bf16x8 b = *reinterpret_cast<const bf16x8*>(Bb + (nt * 16 + lr) * HID + kk * 32 + lg * 8);
      acc[nt] = __builtin_amdgcn_mfma_f32_16x16x32_bf16(a, b, acc[nt], 0, 0, 0);
    }
  }
#pragma unroll
  for (int nt = 0; nt < 16; ++nt)
#pragma unroll
    for (int j = 0; j < 4; ++j)
      P2[(m0 + lg * 4 + j) * ENC + nt * 16 + lr] = f2bf(acc[nt][j]);
}

// ---------------- scores = P2 @ emb^T + pb -> scattered into d_out ----------------
__global__ __launch_bounds__(256) void gemm_scores(const unsigned short* __restrict__ P2,  // [4096,256] bf16
                                                   const unsigned short* __restrict__ E,   // [21844,256] bf16
                                                   const float* __restrict__ pb,
                                                   float* __restrict__ out) {
  int lane = threadIdx.x & 63, w = threadIdx.x >> 6;
  int lr = lane & 15, lg = lane >> 4;
  int m0 = blockIdx.y * 64 + w * 16;
  int n0 = blockIdx.x * 64;
  // A fragments for this wave's 16 rows, full K=256
  bf16x8 a[8];
  const unsigned short* Ap = P2 + (m0 + lr) * ENC + lg * 8;
#pragma unroll
  for (int kk = 0; kk < 8; ++kk) a[kk] = *reinterpret_cast<const bf16x8*>(Ap + kk * 32);

  f32x4 acc[4];
#pragma unroll
  for (int nt = 0; nt < 4; ++nt) {
    int col = n0 + nt * 16 + lr;
    bool ok = col < NNODES;
    const unsigned short* Bp = E + col * ENC + lg * 8;
    f32x4 c = f32x4{0.f, 0.f, 0.f, 0.f};
#pragma unroll
    for (int kk = 0; kk < 8; ++kk) {
      bf16x8 b;
      if (ok) b = *reinterpret_cast<const bf16x8*>(Bp + kk * 32);
      else    b = bf16x8{0, 0, 0, 0, 0, 0, 0, 0};
      c = __builtin_amdgcn_mfma_f32_16x16x32_bf16(a[kk], b, c, 0, 0, 0);
    }
    acc[nt] = c;
  }
  // epilogue: add pb, scatter to permuted output location
  float pbv[4];
#pragma unroll
  for (int j = 0; j < 4; ++j) pbv[j] = pb[m0 + lg * 4 + j];
#pragma unroll
  for (int nt = 0; nt < 4; ++nt) {
    int col = n0 + nt * 16 + lr;
    if (col >= NNODES) continue;
    int nd, ob;
    col_map(col, nd, ob);
#pragma unroll
    for (int j = 0; j < 4; ++j)
      out[ob + (m0 + lg * 4 + j) * nd] = acc[nt][j] + pbv[j];
  }
}

// ---------------- log_softmax in place, one wave per row (ND <= 1024) ----------------
template <int ND>
__global__ __launch_bounds__(256) void lsm_wave(float* __restrict__ out, int obase) {
  constexpr int PER = (ND + 63) / 64;
  int lane = threadIdx.x & 63;
  int row = blockIdx.x * 4 + (threadIdx.x >> 6);
  float* p = out + obase + row * ND;
  float v[PER];
  float m = -3.4e38f;
#pragma unroll
  for (int i = 0; i < PER; ++i) {
    int idx = i * 64 + lane;
    bool ok = (ND % 64 == 0) || (idx < ND);
    v[i] = ok ? p[idx] : -3.4e38f;
    m = fmaxf(m, v[i]);
  }
#pragma unroll
  for (int d = 32; d; d >>= 1) m = fmaxf(m, __shfl_xor(m, d));
  float s = 0.f;
#pragma unroll
  for (int i = 0; i < PER; ++i) { v[i] -= m; s += __expf(v[i]); }
#pragma unroll
  for (int d = 32; d; d >>= 1) s += __shfl_xor(s, d);
  float lse = __logf(s);
#pragma unroll
  for (int i = 0; i < PER; ++i) {
    int idx = i * 64 + lane;
    if ((ND % 64 == 0) || (idx < ND)) p[idx] = v[i] - lse;
  }
}

// ---------------- log_softmax in place, one block per row (ND = 4096 / 16384) ----------------
template <int ND, int NT>
__global__ __launch_bounds__(NT) void lsm_block(float* __restrict__ out, int obase) {
  constexpr int P4 = ND / NT / 4;
  int tid = threadIdx.x;
  float* p = out + obase + (long)blockIdx.x * ND;
  float4* p4 = reinterpret_cast<float4*>(p);
  float4 v[P4];
  float m = -3.4e38f;
#pragma unroll
  for (int i = 0; i < P4; ++i) {
    v[i] = p4[i * NT + tid];
    m = fmaxf(m, fmaxf(fmaxf(v[i].x, v[i].y), fmaxf(v[i].z, v[i].w)));
  }
#pragma unroll
  for (int d = 32; d; d >>= 1) m = fmaxf(m, __shfl_xor(m, d));
  __shared__ float red[NT / 64];
  if ((tid & 63) == 0) red[tid >> 6] = m;
  __syncthreads();
#pragma unroll
  for (int i = 0; i < NT / 64; ++i) m = fmaxf(m, red[i]);
  float s = 0.f;
#pragma unroll
  for (int i = 0; i < P4; ++i)
    s += __expf(v[i].x - m) + __expf(v[i].y - m) + __expf(v[i].z - m) + __expf(v[i].w - m);
#pragma unroll
  for (int d = 32; d; d >>= 1) s += __shfl_xor(s, d);
  __syncthreads();
  if ((tid & 63) == 0) red[tid >> 6] = s;
  __syncthreads();
  s = 0.f;
#pragma unroll
  for (int i = 0; i < NT / 64; ++i) s += red[i];
  float lse = m + __logf(s);
#pragma unroll
  for (int i = 0; i < P4; ++i) {
    float4 o;
    o.x = v[i].x - lse; o.y = v[i].y - lse; o.z = v[i].z - lse; o.w = v[i].w - lse;
    p4[i * NT + tid] = o;
  }
}

// ---------------- time head: log_softmax(prefix @ W_time^T + b_time) ----------------
__global__ __launch_bounds__(256) void time_head(const float* __restrict__ prefix,
                                                 const float* __restrict__ WtT,  // [1024,48]
                                                 const float* __restrict__ bt,
                                                 float* __restrict__ out) {
  int lane = threadIdx.x & 63;
  int row = blockIdx.x * 4 + (threadIdx.x >> 6);
  const float4* pr = reinterpret_cast<const float4*>(prefix + (long)row * HID);
  float acc = -3.4e38f;
  if (lane < NTIMES) {
    float a = 0.f;
#pragma unroll 4
    for (int q = 0; q < HID / 4; ++q) {
      float4 pv = pr[q];
      const float* wrow = WtT + q * 4 * NTIMES;
      a += pv.x * wrow[lane] + pv.y * wrow[NTIMES + lane] +
           pv.z * wrow[2 * NTIMES + lane] + pv.w * wrow[3 * NTIMES + lane];
    }
    acc = a + bt[lane];
  }
  float m = acc;
#pragma unroll
  for (int d = 32; d; d >>= 1) m = fmaxf(m, __shfl_xor(m, d));
  float e = (lane < NTIMES) ? __expf(acc - m) : 0.f;
  float s = e;
#pragma unroll
  for (int d = 32; d; d >>= 1) s += __shfl_xor(s, d);
  if (lane < NTIMES) out[89473024 + row * NTIMES + lane] = acc - m - __logf(s);
}

extern "C" void kernel_launch(void* const* d_in, const int* in_sizes, int n_in,
                              void* d_out, int out_size, void* d_ws, size_t ws_size,
                              hipStream_t stream) {
  const float* prefix = (const float*)d_in[0];  // [128,32,1024]
  const float* emb    = (const float*)d_in[1];  // [21844,256]
  const float* Wk     = (const float*)d_in[2];  // [1024,256]
  const float* bk     = (const float*)d_in[3];  // [1024]
  const float* Wt     = (const float*)d_in[4];  // [48,1024]
  const float* bt     = (const float*)d_in[5];  // [48]
  float* out = (float*)d_out;
  char* ws = (char*)d_ws;

  // workspace layout (all 16B aligned), total ~22.4 MB
  unsigned short* P2   = (unsigned short*)(ws + 0);          // 4096*256 bf16   = 2,097,152 B
  float*          pb   = (float*)(ws + 2097152);             // 4096 f32        = 16,384 B
  unsigned short* Eb   = (unsigned short*)(ws + 2113536);    // 21844*256 bf16  = 11,184,128 B
  unsigned short* WkT  = (unsigned short*)(ws + 13297664);   // 256*1024 bf16   = 524,288 B
  unsigned short* Pb16 = (unsigned short*)(ws + 13821952);   // 4096*1024 bf16  = 8,388,608 B
  float*          WtT  = (float*)(ws + 22210560);            // 1024*48 f32     = 196,608 B

  // preprocessing
  conv_bf16<<<4096, 256, 0, stream>>>(prefix, Pb16, 1048576);
  conv_bf16<<<5461, 256, 0, stream>>>(emb, Eb, 1398016);
  wk_transpose<<<1024, 256, 0, stream>>>(Wk, WkT);
  wt_transpose<<<192, 256, 0, stream>>>(Wt, WtT);
  pb_kernel<<<1024, 256, 0, stream>>>(prefix, bk, pb);

  // P2 = prefix @ W_key (bf16 MFMA)
  p2_mfma<<<64, 256, 0, stream>>>(Pb16, WkT, P2);

  // scores = P2 @ emb^T + pb, scattered into final output layout
  gemm_scores<<<dim3(342, 64), 256, 0, stream>>>(P2, Eb, pb, out);

  // per-depth in-place log_softmax
  lsm_wave<4>    <<<1024, 256, 0, stream>>>(out, 0);
  lsm_wave<16>   <<<1024, 256, 0, stream>>>(out, 16384);
  lsm_wave<64>   <<<1024, 256, 0, stream>>>(out, 81920);
  lsm_wave<256>  <<<1024, 256, 0, stream>>>(out, 344064);
  lsm_wave<1024> <<<1024, 256, 0, stream>>>(out, 1392640);
  lsm_block<4096, 256>  <<<4096, 256,  0, stream>>>(out, 5586944);
  lsm_block<16384, 1024><<<4096, 1024, 0, stream>>>(out, 22364160);

  // time head
  time_head<<<1024, 256, 0, stream>>>(prefix, WtT, bt, out);
}

// Round 2
// 466.292 us; speedup vs baseline: 1.5878x; 1.5878x over previous
//
#include <hip/hip_runtime.h>

#define NNODES 21844
#define ENC 256
#define HID 1024
#define ROWS 4096   // B*S = 128*32
#define NTIMES 48

typedef __attribute__((ext_vector_type(8))) short bf16x8;
typedef __attribute__((ext_vector_type(4))) float f32x4;

__device__ inline unsigned short f2bf(float f) {
  unsigned int u = __float_as_uint(f);
  u += 0x7FFF + ((u >> 16) & 1);   // round-to-nearest-even
  return (unsigned short)(u >> 16);
}

// map global score column -> (depth block size, output base index for row 0)
__device__ inline void col_map(int c, int& nd, int& obase) {
  int off;
  if (c < 340) {
    if (c < 20)  { if (c < 4)   { off = 0;   nd = 4;   } else { off = 4;    nd = 16;   } }
    else         { if (c < 84)  { off = 20;  nd = 64;  } else { off = 84;   nd = 256;  } }
  } else {
    if (c < 5460){ if (c < 1364){ off = 340; nd = 1024;} else { off = 1364; nd = 4096; } }
    else         { off = 5460; nd = 16384; }
  }
  obase = ROWS * off + (c - off);
}

// ---------------- fp32 -> bf16 conversion (vectorized) ----------------
__global__ __launch_bounds__(256) void conv_bf16(const float* __restrict__ in,
                                                 unsigned short* __restrict__ out, int n4) {
  int i = blockIdx.x * 256 + threadIdx.x;
  if (i >= n4) return;
  float4 v = reinterpret_cast<const float4*>(in)[i];
  ushort4 o;
  o.x = f2bf(v.x); o.y = f2bf(v.y); o.z = f2bf(v.z); o.w = f2bf(v.w);
  reinterpret_cast<ushort4*>(out)[i] = o;
}

// ---------------- W_key [1024,256] -> bf16 transposed [256,1024] ----------------
__global__ __launch_bounds__(256) void wk_transpose(const float* __restrict__ Wk,
                                                    unsigned short* __restrict__ WkT) {
  int i = blockIdx.x * 256 + threadIdx.x;     // 262144 total
  int e = i >> 10, h = i & 1023;
  WkT[i] = f2bf(Wk[h * ENC + e]);
}

// ---------------- W_time [48,1024] -> fp32 transposed [1024,48] ----------------
__global__ __launch_bounds__(256) void wt_transpose(const float* __restrict__ Wt,
                                                    float* __restrict__ WtT) {
  int i = blockIdx.x * 256 + threadIdx.x;     // 49152 total
  if (i >= NTIMES * HID) return;
  int k = i / NTIMES, c = i % NTIMES;
  WtT[i] = Wt[c * HID + k];
}

// ---------------- pb[r] = prefix[r,:] . b_key ----------------
__global__ __launch_bounds__(256) void pb_kernel(const float* __restrict__ prefix,
                                                 const float* __restrict__ bk,
                                                 float* __restrict__ pb) {
  int lane = threadIdx.x & 63;
  int r = blockIdx.x * 4 + (threadIdx.x >> 6);
  const float4* pr = reinterpret_cast<const float4*>(prefix + (long)r * HID);
  const float4* bv = reinterpret_cast<const float4*>(bk);
  float s = 0.f;
#pragma unroll
  for (int i = 0; i < 4; ++i) {
    float4 a = pr[lane + 64 * i], b = bv[lane + 64 * i];
    s += a.x * b.x + a.y * b.y + a.z * b.z + a.w * b.w;
  }
#pragma unroll
  for (int d = 32; d; d >>= 1) s += __shfl_xor(s, d);
  if (lane == 0) pb[r] = s;
}

// ---------------- P2 = prefix @ W_key  (bf16 MFMA, K=1024) -> bf16 [4096,256] ----------------
// grid dim3(4, 64): 64x64 output tile per block, 4 waves each 16x64
__global__ __launch_bounds__(256) void p2_mfma(const unsigned short* __restrict__ Ab,   // prefix bf16 [4096,1024]
                                               const unsigned short* __restrict__ Bb,   // W_key^T bf16 [256,1024]
                                               unsigned short* __restrict__ P2) {
  int lane = threadIdx.x & 63, w = threadIdx.x >> 6;
  int lr = lane & 15, lg = lane >> 4;
  int m0 = blockIdx.y * 64 + w * 16;
  int nb = blockIdx.x * 64;
  f32x4 acc[4];
#pragma unroll
  for (int n = 0; n < 4; ++n) acc[n] = f32x4{0.f, 0.f, 0.f, 0.f};
  const unsigned short* Ap = Ab + (long)(m0 + lr) * HID + lg * 8;
  for (int kk = 0; kk < 32; ++kk) {
    bf16x8 a = *reinterpret_cast<const bf16x8*>(Ap + kk * 32);
#pragma unroll
    for (int n = 0; n < 4; ++n) {
      bf16x8 b = *reinterpret_cast<const bf16x8*>(Bb + (long)(nb + n * 16 + lr) * HID + kk * 32 + lg * 8);
      acc[n] = __builtin_amdgcn_mfma_f32_16x16x32_bf16(a, b, acc[n], 0, 0, 0);
    }
  }
#pragma unroll
  for (int n = 0; n < 4; ++n)
#pragma unroll
    for (int j = 0; j < 4; ++j)
      P2[(m0 + lg * 4 + j) * ENC + nb + n * 16 + lr] = f2bf(acc[n][j]);
}

// ---------------- scores = P2 @ emb^T + pb -> scattered into d_out ----------------
// m97-style: 128x128 tile, BK=64, global_load_lds staging, 4 waves each 64x64
__global__ __launch_bounds__(256) void gemm_scores(const unsigned short* __restrict__ P2,  // [4096,256] bf16
                                                   const unsigned short* __restrict__ E,   // [21844,256] bf16
                                                   const float* __restrict__ pb,
                                                   float* __restrict__ out) {
  __shared__ unsigned short As[128 * 64];
  __shared__ unsigned short Bs[128 * 64];
  int tid = threadIdx.x;
  int lane = tid & 63, w = tid >> 6;
  int lr = lane & 15, lg = lane >> 4;
  int wr = w >> 1, wc = w & 1;
  int m0 = blockIdx.y * 128, n0 = blockIdx.x * 128;
  int rr = tid >> 3, c8 = tid & 7;   // 8 lanes per 128B row

  f32x4 acc[4][4];
#pragma unroll
  for (int m = 0; m < 4; ++m)
#pragma unroll
    for (int n = 0; n < 4; ++n) acc[m][n] = f32x4{0.f, 0.f, 0.f, 0.f};

  for (int kt = 0; kt < 4; ++kt) {
    if (kt) __syncthreads();
    // stage A[128][64] and B[128][64]: wave-linear LDS dest, 16B/lane
#pragma unroll
    for (int r = 0; r < 4; ++r) {
      const unsigned short* ga = P2 + (long)(m0 + r * 32 + rr) * ENC + kt * 64 + c8 * 8;
      __builtin_amdgcn_global_load_lds(
          (const __attribute__((address_space(1))) unsigned int*)ga,
          (__attribute__((address_space(3))) unsigned int*)(As + r * 2048 + w * 512), 16, 0, 0);
      int er = n0 + r * 32 + rr;
      if (er > NNODES - 1) er = NNODES - 1;   // clamp: last block reads dup rows (discarded)
      const unsigned short* gb = E + (long)er * ENC + kt * 64 + c8 * 8;
      __builtin_amdgcn_global_load_lds(
          (const __attribute__((address_space(1))) unsigned int*)gb,
          (__attribute__((address_space(3))) unsigned int*)(Bs + r * 2048 + w * 512), 16, 0, 0);
    }
    __syncthreads();   // compiler drains vmcnt before s_barrier
#pragma unroll
    for (int kk = 0; kk < 2; ++kk) {
      bf16x8 a[4], b[4];
#pragma unroll
      for (int m = 0; m < 4; ++m)
        a[m] = *reinterpret_cast<const bf16x8*>(As + (wr * 64 + m * 16 + lr) * 64 + kk * 32 + lg * 8);
#pragma unroll
      for (int n = 0; n < 4; ++n)
        b[n] = *reinterpret_cast<const bf16x8*>(Bs + (wc * 64 + n * 16 + lr) * 64 + kk * 32 + lg * 8);
#pragma unroll
      for (int m = 0; m < 4; ++m)
#pragma unroll
        for (int n = 0; n < 4; ++n)
          acc[m][n] = __builtin_amdgcn_mfma_f32_16x16x32_bf16(a[m], b[n], acc[m][n], 0, 0, 0);
    }
  }

  // epilogue: add pb, scatter to permuted output location
  int rbase = m0 + wr * 64 + lg * 4;
  int cbase = n0 + wc * 64 + lr;
  float pbv[4][4];
#pragma unroll
  for (int m = 0; m < 4; ++m)
#pragma unroll
    for (int j = 0; j < 4; ++j) pbv[m][j] = pb[rbase + m * 16 + j];
#pragma unroll
  for (int n = 0; n < 4; ++n) {
    int gc = cbase + n * 16;
    if (gc < NNODES) {
      int nd, ob;
      col_map(gc, nd, ob);
#pragma unroll
      for (int m = 0; m < 4; ++m)
#pragma unroll
        for (int j = 0; j < 4; ++j)
          out[ob + (rbase + m * 16 + j) * nd] = acc[m][n][j] + pbv[m][j];
    }
  }
}

// ---------------- log_softmax in place, one wave per row (ND <= 1024) ----------------
template <int ND>
__global__ __launch_bounds__(256) void lsm_wave(float* __restrict__ out, int obase) {
  constexpr int PER = (ND + 63) / 64;
  int lane = threadIdx.x & 63;
  int row = blockIdx.x * 4 + (threadIdx.x >> 6);
  float* p = out + obase + row * ND;
  float v[PER];
  float m = -3.4e38f;
#pragma unroll
  for (int i = 0; i < PER; ++i) {
    int idx = i * 64 + lane;
    bool ok = (ND % 64 == 0) || (idx < ND);
    v[i] = ok ? p[idx] : -3.4e38f;
    m = fmaxf(m, v[i]);
  }
#pragma unroll
  for (int d = 32; d; d >>= 1) m = fmaxf(m, __shfl_xor(m, d));
  float s = 0.f;
#pragma unroll
  for (int i = 0; i < PER; ++i) { v[i] -= m; s += __expf(v[i]); }
#pragma unroll
  for (int d = 32; d; d >>= 1) s += __shfl_xor(s, d);
  float lse = __logf(s);
#pragma unroll
  for (int i = 0; i < PER; ++i) {
    int idx = i * 64 + lane;
    if ((ND % 64 == 0) || (idx < ND)) p[idx] = v[i] - lse;
  }
}

// ---------------- log_softmax in place, one block per row (ND = 4096 / 16384) ----------------
template <int ND, int NT>
__global__ __launch_bounds__(NT) void lsm_block(float* __restrict__ out, int obase) {
  constexpr int P4 = ND / NT / 4;
  int tid = threadIdx.x;
  float* p = out + obase + (long)blockIdx.x * ND;
  float4* p4 = reinterpret_cast<float4*>(p);
  float4 v[P4];
  float m = -3.4e38f;
#pragma unroll
  for (int i = 0; i < P4; ++i) {
    v[i] = p4[i * NT + tid];
    m = fmaxf(m, fmaxf(fmaxf(v[i].x, v[i].y), fmaxf(v[i].z, v[i].w)));
  }
#pragma unroll
  for (int d = 32; d; d >>= 1) m = fmaxf(m, __shfl_xor(m, d));
  __shared__ float red[NT / 64];
  if ((tid & 63) == 0) red[tid >> 6] = m;
  __syncthreads();
#pragma unroll
  for (int i = 0; i < NT / 64; ++i) m = fmaxf(m, red[i]);
  float s = 0.f;
#pragma unroll
  for (int i = 0; i < P4; ++i)
    s += __expf(v[i].x - m) + __expf(v[i].y - m) + __expf(v[i].z - m) + __expf(v[i].w - m);
#pragma unroll
  for (int d = 32; d; d >>= 1) s += __shfl_xor(s, d);
  __syncthreads();
  if ((tid & 63) == 0) red[tid >> 6] = s;
  __syncthreads();
  s = 0.f;
#pragma unroll
  for (int i = 0; i < NT / 64; ++i) s += red[i];
  float lse = m + __logf(s);
#pragma unroll
  for (int i = 0; i < P4; ++i) {
    float4 o;
    o.x = v[i].x - lse; o.y = v[i].y - lse; o.z = v[i].z - lse; o.w = v[i].w - lse;
    p4[i * NT + tid] = o;
  }
}

// ---------------- time head: log_softmax(prefix @ W_time^T + b_time) ----------------
__global__ __launch_bounds__(256) void time_head(const float* __restrict__ prefix,
                                                 const float* __restrict__ WtT,  // [1024,48]
                                                 const float* __restrict__ bt,
                                                 float* __restrict__ out) {
  int lane = threadIdx.x & 63;
  int row = blockIdx.x * 4 + (threadIdx.x >> 6);
  const float4* pr = reinterpret_cast<const float4*>(prefix + (long)row * HID);
  float acc = -3.4e38f;
  if (lane < NTIMES) {
    float a = 0.f;
#pragma unroll 4
    for (int q = 0; q < HID / 4; ++q) {
      float4 pv = pr[q];
      const float* wrow = WtT + q * 4 * NTIMES;
      a += pv.x * wrow[lane] + pv.y * wrow[NTIMES + lane] +
           pv.z * wrow[2 * NTIMES + lane] + pv.w * wrow[3 * NTIMES + lane];
    }
    acc = a + bt[lane];
  }
  float m = acc;
#pragma unroll
  for (int d = 32; d; d >>= 1) m = fmaxf(m, __shfl_xor(m, d));
  float e = (lane < NTIMES) ? __expf(acc - m) : 0.f;
  float s = e;
#pragma unroll
  for (int d = 32; d; d >>= 1) s += __shfl_xor(s, d);
  if (lane < NTIMES) out[89473024 + row * NTIMES + lane] = acc - m - __logf(s);
}

extern "C" void kernel_launch(void* const* d_in, const int* in_sizes, int n_in,
                              void* d_out, int out_size, void* d_ws, size_t ws_size,
                              hipStream_t stream) {
  const float* prefix = (const float*)d_in[0];  // [128,32,1024]
  const float* emb    = (const float*)d_in[1];  // [21844,256]
  const float* Wk     = (const float*)d_in[2];  // [1024,256]
  const float* bk     = (const float*)d_in[3];  // [1024]
  const float* Wt     = (const float*)d_in[4];  // [48,1024]
  const float* bt     = (const float*)d_in[5];  // [48]
  float* out = (float*)d_out;
  char* ws = (char*)d_ws;

  // workspace layout (all 16B aligned), total ~22.4 MB
  unsigned short* P2   = (unsigned short*)(ws + 0);          // 4096*256 bf16   = 2,097,152 B
  float*          pb   = (float*)(ws + 2097152);             // 4096 f32        = 16,384 B
  unsigned short* Eb   = (unsigned short*)(ws + 2113536);    // 21844*256 bf16  = 11,184,128 B
  unsigned short* WkT  = (unsigned short*)(ws + 13297664);   // 256*1024 bf16   = 524,288 B
  unsigned short* Pb16 = (unsigned short*)(ws + 13821952);   // 4096*1024 bf16  = 8,388,608 B
  float*          WtT  = (float*)(ws + 22210560);            // 1024*48 f32     = 196,608 B

  // preprocessing
  conv_bf16<<<4096, 256, 0, stream>>>(prefix, Pb16, 1048576);
  conv_bf16<<<5461, 256, 0, stream>>>(emb, Eb, 1398016);
  wk_transpose<<<1024, 256, 0, stream>>>(Wk, WkT);
  wt_transpose<<<192, 256, 0, stream>>>(Wt, WtT);
  pb_kernel<<<1024, 256, 0, stream>>>(prefix, bk, pb);

  // P2 = prefix @ W_key (bf16 MFMA)
  p2_mfma<<<dim3(4, 64), 256, 0, stream>>>(Pb16, WkT, P2);

  // scores = P2 @ emb^T + pb, scattered into final output layout
  gemm_scores<<<dim3(171, 32), 256, 0, stream>>>(P2, Eb, pb, out);

  // per-depth in-place log_softmax
  lsm_wave<4>    <<<1024, 256, 0, stream>>>(out, 0);
  lsm_wave<16>   <<<1024, 256, 0, stream>>>(out, 16384);
  lsm_wave<64>   <<<1024, 256, 0, stream>>>(out, 81920);
  lsm_wave<256>  <<<1024, 256, 0, stream>>>(out, 344064);
  lsm_wave<1024> <<<1024, 256, 0, stream>>>(out, 1392640);
  lsm_block<4096, 256>  <<<4096, 256,  0, stream>>>(out, 5586944);
  lsm_block<16384, 1024><<<4096, 1024, 0, stream>>>(out, 22364160);

  // time head
  time_head<<<1024, 256, 0, stream>>>(prefix, WtT, bt, out);
}

// Round 3
// 366.758 us; speedup vs baseline: 2.0187x; 1.2714x over previous
//
#include <hip/hip_runtime.h>

#define NNODES 21844
#define ENC 256
#define HID 1024
#define ROWS 4096   // B*S = 128*32
#define NTIMES 48

typedef __attribute__((ext_vector_type(8))) short bf16x8;
typedef __attribute__((ext_vector_type(4))) float f32x4;

__device__ const int g_off[8] = {0, 4, 20, 84, 340, 1364, 5460, 21844};
__device__ const int g_l2[7]  = {2, 4, 6, 8, 10, 12, 14};

__device__ inline unsigned short f2bf(float f) {
  unsigned int u = __float_as_uint(f);
  u += 0x7FFF + ((u >> 16) & 1);   // round-to-nearest-even
  return (unsigned short)(u >> 16);
}

// depth index 0..6 for a global score column
__device__ inline int depth_of(int c) {
  return (c >= 4) + (c >= 20) + (c >= 84) + (c >= 340) + (c >= 1364) + (c >= 5460);
}

// ---------------- fused preprocessing: bf16 conversions + transposes ----------------
__global__ __launch_bounds__(256) void prep(const float* __restrict__ prefix,
                                            const float* __restrict__ emb,
                                            const float* __restrict__ Wk,
                                            const float* __restrict__ Wt,
                                            unsigned short* __restrict__ Pb16,
                                            unsigned short* __restrict__ Eb,
                                            unsigned short* __restrict__ WkT,
                                            float* __restrict__ WtT) {
  int bid = blockIdx.x, tid = threadIdx.x;
  if (bid < 4096) {                          // prefix fp32 -> bf16 (float4 packs)
    int i = bid * 256 + tid;
    float4 v = reinterpret_cast<const float4*>(prefix)[i];
    ushort4 o; o.x = f2bf(v.x); o.y = f2bf(v.y); o.z = f2bf(v.z); o.w = f2bf(v.w);
    reinterpret_cast<ushort4*>(Pb16)[i] = o;
  } else if (bid < 9557) {                   // emb fp32 -> bf16
    int i = (bid - 4096) * 256 + tid;
    float4 v = reinterpret_cast<const float4*>(emb)[i];
    ushort4 o; o.x = f2bf(v.x); o.y = f2bf(v.y); o.z = f2bf(v.z); o.w = f2bf(v.w);
    reinterpret_cast<ushort4*>(Eb)[i] = o;
  } else if (bid < 10581) {                  // W_key [1024,256] -> bf16 T [256,1024]
    int i = (bid - 9557) * 256 + tid;
    int e = i >> 10, h = i & 1023;
    WkT[i] = f2bf(Wk[h * ENC + e]);
  } else {                                   // W_time [48,1024] -> f32 T [1024,48]
    int i = (bid - 10581) * 256 + tid;
    int k = i / NTIMES, c = i % NTIMES;
    WtT[i] = Wt[c * HID + k];
  }
}

// ---------------- P2 = prefix @ W_key  (bf16 MFMA, K=1024) -> bf16 [4096,256] ----------------
__global__ __launch_bounds__(256) void p2_mfma(const unsigned short* __restrict__ Ab,
                                               const unsigned short* __restrict__ Bb,
                                               unsigned short* __restrict__ P2) {
  int lane = threadIdx.x & 63, w = threadIdx.x >> 6;
  int lr = lane & 15, lg = lane >> 4;
  int m0 = blockIdx.y * 64 + w * 16;
  int nb = blockIdx.x * 64;
  f32x4 acc[4];
#pragma unroll
  for (int n = 0; n < 4; ++n) acc[n] = f32x4{0.f, 0.f, 0.f, 0.f};
  const unsigned short* Ap = Ab + (long)(m0 + lr) * HID + lg * 8;
  for (int kk = 0; kk < 32; ++kk) {
    bf16x8 a = *reinterpret_cast<const bf16x8*>(Ap + kk * 32);
#pragma unroll
    for (int n = 0; n < 4; ++n) {
      bf16x8 b = *reinterpret_cast<const bf16x8*>(Bb + (long)(nb + n * 16 + lr) * HID + kk * 32 + lg * 8);
      acc[n] = __builtin_amdgcn_mfma_f32_16x16x32_bf16(a, b, acc[n], 0, 0, 0);
    }
  }
#pragma unroll
  for (int n = 0; n < 4; ++n)
#pragma unroll
    for (int j = 0; j < 4; ++j)
      P2[(m0 + lg * 4 + j) * ENC + nb + n * 16 + lr] = f2bf(acc[n][j]);
}

// shared GEMM tile body (must be textually identical in both passes for bitwise-equal acc)
#define GEMM_TILE_BODY                                                                     \
  __shared__ unsigned short As[128 * 64];                                                  \
  __shared__ unsigned short Bs[128 * 64];                                                  \
  int tid = threadIdx.x;                                                                   \
  int lane = tid & 63, w = tid >> 6;                                                       \
  int lr = lane & 15, lg = lane >> 4;                                                      \
  int wr = w >> 1, wc = w & 1;                                                             \
  int m0 = blockIdx.x * 128, n0 = blockIdx.y * 128;                                        \
  int rr = tid >> 3, c8 = tid & 7;                                                         \
  f32x4 acc[4][4];                                                                         \
  _Pragma("unroll") for (int m = 0; m < 4; ++m)                                            \
    _Pragma("unroll") for (int n = 0; n < 4; ++n) acc[m][n] = f32x4{0.f, 0.f, 0.f, 0.f};   \
  for (int kt = 0; kt < 4; ++kt) {                                                         \
    if (kt) __syncthreads();                                                               \
    _Pragma("unroll") for (int r = 0; r < 4; ++r) {                                        \
      const unsigned short* ga = P2 + (long)(m0 + r * 32 + rr) * ENC + kt * 64 + c8 * 8;   \
      __builtin_amdgcn_global_load_lds(                                                    \
          (const __attribute__((address_space(1))) unsigned int*)ga,                       \
          (__attribute__((address_space(3))) unsigned int*)(As + r * 2048 + w * 512),      \
          16, 0, 0);                                                                       \
      int er = n0 + r * 32 + rr;                                                           \
      if (er > NNODES - 1) er = NNODES - 1;                                                \
      const unsigned short* gb = E + (long)er * ENC + kt * 64 + c8 * 8;                    \
      __builtin_amdgcn_global_load_lds(                                                    \
          (const __attribute__((address_space(1))) unsigned int*)gb,                       \
          (__attribute__((address_space(3))) unsigned int*)(Bs + r * 2048 + w * 512),      \
          16, 0, 0);                                                                       \
    }                                                                                      \
    __syncthreads();                                                                       \
    _Pragma("unroll") for (int kk = 0; kk < 2; ++kk) {                                     \
      bf16x8 a[4], b[4];                                                                   \
      _Pragma("unroll") for (int m = 0; m < 4; ++m)                                        \
        a[m] = *reinterpret_cast<const bf16x8*>(As + (wr * 64 + m * 16 + lr) * 64 + kk * 32 + lg * 8); \
      _Pragma("unroll") for (int n = 0; n < 4; ++n)                                        \
        b[n] = *reinterpret_cast<const bf16x8*>(Bs + (wc * 64 + n * 16 + lr) * 64 + kk * 32 + lg * 8); \
      _Pragma("unroll") for (int m = 0; m < 4; ++m)                                        \
        _Pragma("unroll") for (int n = 0; n < 4; ++n)                                      \
          acc[m][n] = __builtin_amdgcn_mfma_f32_16x16x32_bf16(a[m], b[n], acc[m][n], 0, 0, 0); \
    }                                                                                      \
  }

// ---------------- pass A: GEMM compute + per-(row,depth) exp-sum partials ----------------
__global__ __launch_bounds__(256) void gemm_lse(const unsigned short* __restrict__ P2,
                                                const unsigned short* __restrict__ E,
                                                float* __restrict__ S) {
  GEMM_TILE_BODY
  // epilogue: masked exp-sums per row per depth, 16-lane reduce, atomicAdd
  int rbase = m0 + wr * 64 + lg * 4;
  int hstart = n0 + wc * 64;
  int dlo = depth_of(hstart);
  int hend = hstart + 63; if (hend > NNODES - 1) hend = NNODES - 1;
  int dhi = depth_of(hend);
  int cd[4];
#pragma unroll
  for (int n = 0; n < 4; ++n) {
    int gc = hstart + n * 16 + lr;
    cd[n] = (gc < NNODES) ? depth_of(gc) : 99;
  }
  // exp in place
#pragma unroll
  for (int m = 0; m < 4; ++m)
#pragma unroll
    for (int n = 0; n < 4; ++n)
#pragma unroll
      for (int j = 0; j < 4; ++j) acc[m][n][j] = __expf(acc[m][n][j]);
  for (int dt = dlo; dt <= dhi; ++dt) {
#pragma unroll
    for (int m = 0; m < 4; ++m) {
      float s[4] = {0.f, 0.f, 0.f, 0.f};
#pragma unroll
      for (int n = 0; n < 4; ++n) {
        bool use = (cd[n] == dt);
#pragma unroll
        for (int j = 0; j < 4; ++j) s[j] += use ? acc[m][n][j] : 0.f;
      }
#pragma unroll
      for (int j = 0; j < 4; ++j)
#pragma unroll
        for (int o = 1; o < 16; o <<= 1) s[j] += __shfl_xor(s[j], o);
      if (lr == 0) {
#pragma unroll
        for (int j = 0; j < 4; ++j)
          atomicAdd(&S[dt * ROWS + rbase + m * 16 + j], s[j]);
      }
    }
  }
}

// ---------------- lse = log(S) ----------------
__global__ __launch_bounds__(256) void lse_log(const float* __restrict__ S,
                                               float* __restrict__ L) {
  int i = blockIdx.x * 256 + threadIdx.x;   // 7*4096 = 28672 = 112*256
  L[i] = __logf(S[i]);
}

// ---------------- pass B: GEMM recompute + write (acc - lse) to final layout ----------------
__global__ __launch_bounds__(256) void gemm_write(const unsigned short* __restrict__ P2,
                                                  const unsigned short* __restrict__ E,
                                                  const float* __restrict__ Lse,
                                                  float* __restrict__ out) {
  GEMM_TILE_BODY
  int rbase = m0 + wr * 64 + lg * 4;
  int hstart = n0 + wc * 64;
#pragma unroll
  for (int n = 0; n < 4; ++n) {
    int gc = hstart + n * 16 + lr;
    if (gc >= NNODES) continue;
    int d = depth_of(gc);
    long ob = ((long)g_off[d] << 12) + (gc - g_off[d]);
    int sh = g_l2[d];
    const float* lp = Lse + d * ROWS;
#pragma unroll
    for (int m = 0; m < 4; ++m)
#pragma unroll
      for (int j = 0; j < 4; ++j) {
        int row = rbase + m * 16 + j;
        out[ob + ((long)row << sh)] = acc[m][n][j] - lp[row];
      }
  }
}

// ---------------- time head: log_softmax(prefix @ W_time^T + b_time) ----------------
__global__ __launch_bounds__(256) void time_head(const float* __restrict__ prefix,
                                                 const float* __restrict__ WtT,
                                                 const float* __restrict__ bt,
                                                 float* __restrict__ out) {
  int lane = threadIdx.x & 63;
  int row = blockIdx.x * 4 + (threadIdx.x >> 6);
  const float4* pr = reinterpret_cast<const float4*>(prefix + (long)row * HID);
  float acc = -3.4e38f;
  if (lane < NTIMES) {
    float a = 0.f;
#pragma unroll 4
    for (int q = 0; q < HID / 4; ++q) {
      float4 pv = pr[q];
      const float* wrow = WtT + q * 4 * NTIMES;
      a += pv.x * wrow[lane] + pv.y * wrow[NTIMES + lane] +
           pv.z * wrow[2 * NTIMES + lane] + pv.w * wrow[3 * NTIMES + lane];
    }
    acc = a + bt[lane];
  }
  float m = acc;
#pragma unroll
  for (int d = 32; d; d >>= 1) m = fmaxf(m, __shfl_xor(m, d));
  float e = (lane < NTIMES) ? __expf(acc - m) : 0.f;
  float s = e;
#pragma unroll
  for (int d = 32; d; d >>= 1) s += __shfl_xor(s, d);
  if (lane < NTIMES) out[89473024 + row * NTIMES + lane] = acc - m - __logf(s);
}

extern "C" void kernel_launch(void* const* d_in, const int* in_sizes, int n_in,
                              void* d_out, int out_size, void* d_ws, size_t ws_size,
                              hipStream_t stream) {
  const float* prefix = (const float*)d_in[0];  // [128,32,1024]
  const float* emb    = (const float*)d_in[1];  // [21844,256]
  const float* Wk     = (const float*)d_in[2];  // [1024,256]
  const float* Wt     = (const float*)d_in[4];  // [48,1024]
  const float* bt     = (const float*)d_in[5];  // [48]
  float* out = (float*)d_out;
  char* ws = (char*)d_ws;

  // workspace layout (16B aligned)
  unsigned short* P2   = (unsigned short*)(ws + 0);          // 4096*256 bf16
  unsigned short* Eb   = (unsigned short*)(ws + 2097152);    // 21844*256 bf16
  unsigned short* WkT  = (unsigned short*)(ws + 13281280);   // 256*1024 bf16
  unsigned short* Pb16 = (unsigned short*)(ws + 13805568);   // 4096*1024 bf16
  float*          WtT  = (float*)(ws + 22194176);            // 1024*48 f32
  float*          S    = (float*)(ws + 22390784);            // 7*4096 f32
  float*          Lse  = (float*)(ws + 22505472);            // 7*4096 f32

  hipMemsetAsync(S, 0, 7 * ROWS * sizeof(float), stream);

  prep<<<10773, 256, 0, stream>>>(prefix, emb, Wk, Wt, Pb16, Eb, WkT, WtT);

  p2_mfma<<<dim3(4, 64), 256, 0, stream>>>(Pb16, WkT, P2);

  // pass A: exp-sum partials (no score write)
  gemm_lse<<<dim3(32, 171), 256, 0, stream>>>(P2, Eb, S);

  lse_log<<<112, 256, 0, stream>>>(S, Lse);

  // pass B: recompute + single coalesced-permuted write of log-softmax
  gemm_write<<<dim3(32, 171), 256, 0, stream>>>(P2, Eb, Lse, out);

  time_head<<<1024, 256, 0, stream>>>(prefix, WtT, bt, out);
}

// Round 4
// 345.701 us; speedup vs baseline: 2.1417x; 1.0609x over previous
//
#include <hip/hip_runtime.h>

#define NNODES 21844
#define ENC 256
#define HID 1024
#define ROWS 4096   // B*S = 128*32
#define NTIMES 48

typedef __attribute__((ext_vector_type(8))) short bf16x8;
typedef __attribute__((ext_vector_type(8))) unsigned short u16x8;
typedef __attribute__((ext_vector_type(4))) float f32x4;

__device__ const int g_off[8] = {0, 4, 20, 84, 340, 1364, 5460, 21844};

__device__ inline unsigned short f2bf(float f) {
  unsigned int u = __float_as_uint(f);
  u += 0x7FFF + ((u >> 16) & 1);   // round-to-nearest-even
  return (unsigned short)(u >> 16);
}

__device__ inline int depth_of(int c) {
  return (c >= 4) + (c >= 20) + (c >= 84) + (c >= 340) + (c >= 1364) + (c >= 5460);
}

// ---------------- fused preprocessing: conversions + transposes + S zeroing ----------------
__global__ __launch_bounds__(256) void prep(const float* __restrict__ prefix,
                                            const float* __restrict__ emb,
                                            const float* __restrict__ Wk,
                                            const float* __restrict__ Wt,
                                            unsigned short* __restrict__ Pb16,
                                            unsigned short* __restrict__ Eb,
                                            unsigned short* __restrict__ WkT,
                                            float* __restrict__ WtT,
                                            float* __restrict__ S) {
  int bid = blockIdx.x, tid = threadIdx.x;
  if (bid < 4096) {                          // prefix fp32 -> bf16
    int i = bid * 256 + tid;
    float4 v = reinterpret_cast<const float4*>(prefix)[i];
    ushort4 o; o.x = f2bf(v.x); o.y = f2bf(v.y); o.z = f2bf(v.z); o.w = f2bf(v.w);
    reinterpret_cast<ushort4*>(Pb16)[i] = o;
  } else if (bid < 9557) {                   // emb fp32 -> bf16
    int i = (bid - 4096) * 256 + tid;
    float4 v = reinterpret_cast<const float4*>(emb)[i];
    ushort4 o; o.x = f2bf(v.x); o.y = f2bf(v.y); o.z = f2bf(v.z); o.w = f2bf(v.w);
    reinterpret_cast<ushort4*>(Eb)[i] = o;
  } else if (bid < 10581) {                  // W_key [1024,256] -> bf16 T [256,1024]
    int i = (bid - 9557) * 256 + tid;
    int e = i >> 10, h = i & 1023;
    WkT[i] = f2bf(Wk[h * ENC + e]);
  } else if (bid < 10773) {                  // W_time [48,1024] -> f32 T [1024,48]
    int i = (bid - 10581) * 256 + tid;
    int k = i / NTIMES, c = i % NTIMES;
    WtT[i] = Wt[c * HID + k];
  } else {                                   // zero S (7*4096 floats = 7168 float4)
    int i = (bid - 10773) * 256 + tid;
    reinterpret_cast<float4*>(S)[i] = float4{0.f, 0.f, 0.f, 0.f};
  }
}

// ---------------- P2 = prefix @ W_key  (bf16 MFMA, K=1024) -> bf16 [4096,256] ----------------
__global__ __launch_bounds__(256) void p2_mfma(const unsigned short* __restrict__ Ab,
                                               const unsigned short* __restrict__ Bb,
                                               unsigned short* __restrict__ P2) {
  int lane = threadIdx.x & 63, w = threadIdx.x >> 6;
  int lr = lane & 15, lg = lane >> 4;
  int m0 = blockIdx.y * 64 + w * 16;
  int nb = blockIdx.x * 64;
  f32x4 acc[4];
#pragma unroll
  for (int n = 0; n < 4; ++n) acc[n] = f32x4{0.f, 0.f, 0.f, 0.f};
  const unsigned short* Ap = Ab + (long)(m0 + lr) * HID + lg * 8;
  for (int kk = 0; kk < 32; ++kk) {
    bf16x8 a = *reinterpret_cast<const bf16x8*>(Ap + kk * 32);
#pragma unroll
    for (int n = 0; n < 4; ++n) {
      bf16x8 b = *reinterpret_cast<const bf16x8*>(Bb + (long)(nb + n * 16 + lr) * HID + kk * 32 + lg * 8);
      acc[n] = __builtin_amdgcn_mfma_f32_16x16x32_bf16(a, b, acc[n], 0, 0, 0);
    }
  }
#pragma unroll
  for (int n = 0; n < 4; ++n)
#pragma unroll
    for (int j = 0; j < 4; ++j)
      P2[(m0 + lg * 4 + j) * ENC + nb + n * 16 + lr] = f2bf(acc[n][j]);
}

#define GEMM_TILE_BODY                                                                     \
  __shared__ unsigned short As[128 * 64];                                                  \
  __shared__ unsigned short Bs[128 * 64];                                                  \
  int tid = threadIdx.x;                                                                   \
  int lane = tid & 63, w = tid >> 6;                                                       \
  int lr = lane & 15, lg = lane >> 4;                                                      \
  int wr = w >> 1, wc = w & 1;                                                             \
  int m0 = blockIdx.x * 128, n0 = blockIdx.y * 128;                                        \
  int rr = tid >> 3, c8 = tid & 7;                                                         \
  f32x4 acc[4][4];                                                                         \
  _Pragma("unroll") for (int m = 0; m < 4; ++m)                                            \
    _Pragma("unroll") for (int n = 0; n < 4; ++n) acc[m][n] = f32x4{0.f, 0.f, 0.f, 0.f};   \
  for (int kt = 0; kt < 4; ++kt) {                                                         \
    if (kt) __syncthreads();                                                               \
    _Pragma("unroll") for (int r = 0; r < 4; ++r) {                                        \
      const unsigned short* ga = P2 + (long)(m0 + r * 32 + rr) * ENC + kt * 64 + c8 * 8;   \
      __builtin_amdgcn_global_load_lds(                                                    \
          (const __attribute__((address_space(1))) unsigned int*)ga,                       \
          (__attribute__((address_space(3))) unsigned int*)(As + r * 2048 + w * 512),      \
          16, 0, 0);                                                                       \
      int er = n0 + r * 32 + rr;                                                           \
      if (er > NNODES - 1) er = NNODES - 1;                                                \
      const unsigned short* gb = E + (long)er * ENC + kt * 64 + c8 * 8;                    \
      __builtin_amdgcn_global_load_lds(                                                    \
          (const __attribute__((address_space(1))) unsigned int*)gb,                       \
          (__attribute__((address_space(3))) unsigned int*)(Bs + r * 2048 + w * 512),      \
          16, 0, 0);                                                                       \
    }                                                                                      \
    __syncthreads();                                                                       \
    _Pragma("unroll") for (int kk = 0; kk < 2; ++kk) {                                     \
      bf16x8 a[4], b[4];                                                                   \
      _Pragma("unroll") for (int m = 0; m < 4; ++m)                                        \
        a[m] = *reinterpret_cast<const bf16x8*>(As + (wr * 64 + m * 16 + lr) * 64 + kk * 32 + lg * 8); \
      _Pragma("unroll") for (int n = 0; n < 4; ++n)                                        \
        b[n] = *reinterpret_cast<const bf16x8*>(Bs + (wc * 64 + n * 16 + lr) * 64 + kk * 32 + lg * 8); \
      _Pragma("unroll") for (int m = 0; m < 4; ++m)                                        \
        _Pragma("unroll") for (int n = 0; n < 4; ++n)                                      \
          acc[m][n] = __builtin_amdgcn_mfma_f32_16x16x32_bf16(a[m], b[n], acc[m][n], 0, 0, 0); \
    }                                                                                      \
  }

// ---------------- single GEMM pass: stash raw scores + per-(row,depth) exp-sum atomics ----------------
template <int BF16S>
__global__ __launch_bounds__(256) void gemm_stash(const unsigned short* __restrict__ P2,
                                                  const unsigned short* __restrict__ E,
                                                  unsigned short* __restrict__ stash,
                                                  float* __restrict__ outp,
                                                  float* __restrict__ S) {
  GEMM_TILE_BODY
  int rbase = m0 + wr * 64 + lg * 4;
  int hstart = n0 + wc * 64;
  // write raw scores to stash (bf16) or out (fp32), final permuted layout
#pragma unroll
  for (int n = 0; n < 4; ++n) {
    int gc = hstart + n * 16 + lr;
    if (gc < NNODES) {
      int d = depth_of(gc);
      long ob = ((long)g_off[d] << 12) + (gc - g_off[d]);
      int sh = 2 * (d + 1);
#pragma unroll
      for (int m = 0; m < 4; ++m)
#pragma unroll
        for (int j = 0; j < 4; ++j) {
          int row = rbase + m * 16 + j;
          long idx = ob + ((long)row << sh);
          if (BF16S) stash[idx] = f2bf(acc[m][n][j]);
          else       outp[idx]  = acc[m][n][j];
        }
    }
  }
  // exp-sum partials (fp32 acc), 16-lane reduce, atomicAdd
  int dlo = depth_of(hstart);
  int hend = hstart + 63; if (hend > NNODES - 1) hend = NNODES - 1;
  int dhi = depth_of(hend);
  int cd[4];
#pragma unroll
  for (int n = 0; n < 4; ++n) {
    int gc = hstart + n * 16 + lr;
    cd[n] = (gc < NNODES) ? depth_of(gc) : 99;
  }
#pragma unroll
  for (int m = 0; m < 4; ++m)
#pragma unroll
    for (int n = 0; n < 4; ++n)
#pragma unroll
      for (int j = 0; j < 4; ++j) acc[m][n][j] = __expf(acc[m][n][j]);
  for (int dt = dlo; dt <= dhi; ++dt) {
#pragma unroll
    for (int m = 0; m < 4; ++m) {
      float s[4] = {0.f, 0.f, 0.f, 0.f};
#pragma unroll
      for (int n = 0; n < 4; ++n) {
        bool use = (cd[n] == dt);
#pragma unroll
        for (int j = 0; j < 4; ++j) s[j] += use ? acc[m][n][j] : 0.f;
      }
#pragma unroll
      for (int j = 0; j < 4; ++j)
#pragma unroll
        for (int o = 1; o < 16; o <<= 1) s[j] += __shfl_xor(s[j], o);
      if (lr == 0) {
#pragma unroll
        for (int j = 0; j < 4; ++j)
          atomicAdd(&S[dt * ROWS + rbase + m * 16 + j], s[j]);
      }
    }
  }
}

// ---------------- pass B: out = stash - log(S[row,depth]), streaming ----------------
// 2048 contiguous elements per block; all depth-region boundaries are multiples of 2048
template <int BF16S>
__global__ __launch_bounds__(256) void sub_write(const unsigned short* __restrict__ stash,
                                                 const float* __restrict__ S,
                                                 float* __restrict__ out) {
  long base = (long)blockIdx.x * 2048 + threadIdx.x * 8;
  int d = (base >= 16384) + (base >= 81920) + (base >= 344064) +
          (base >= 1392640) + (base >= 5586944) + (base >= 22364160);
  long bd = (d == 0) ? 0L : (d == 1) ? 16384L : (d == 2) ? 81920L : (d == 3) ? 344064L
          : (d == 4) ? 1392640L : (d == 5) ? 5586944L : 22364160L;
  long rel = base - bd;
  const float* sp = S + d * ROWS;
  float v[8];
  if (BF16S) {
    u16x8 u = *reinterpret_cast<const u16x8*>(stash + base);
#pragma unroll
    for (int j = 0; j < 8; ++j) v[j] = __uint_as_float((unsigned)(unsigned short)u[j] << 16);
  } else {
    float4 a = reinterpret_cast<const float4*>(out + base)[0];
    float4 b = reinterpret_cast<const float4*>(out + base)[1];
    v[0] = a.x; v[1] = a.y; v[2] = a.z; v[3] = a.w;
    v[4] = b.x; v[5] = b.y; v[6] = b.z; v[7] = b.w;
  }
  float4 o0, o1;
  if (d == 0) {            // nd=4: 8 elements span rows r0, r0+1
    int r0 = (int)(rel >> 2);
    float l0 = __logf(sp[r0]), l1 = __logf(sp[r0 + 1]);
    o0 = float4{v[0] - l0, v[1] - l0, v[2] - l0, v[3] - l0};
    o1 = float4{v[4] - l1, v[5] - l1, v[6] - l1, v[7] - l1};
  } else {
    int row = (int)(rel >> (2 * (d + 1)));
    float l = __logf(sp[row]);
    o0 = float4{v[0] - l, v[1] - l, v[2] - l, v[3] - l};
    o1 = float4{v[4] - l, v[5] - l, v[6] - l, v[7] - l};
  }
  reinterpret_cast<float4*>(out + base)[0] = o0;
  reinterpret_cast<float4*>(out + base)[1] = o1;
}

// ---------------- time head: log_softmax(prefix @ W_time^T + b_time) ----------------
__global__ __launch_bounds__(256) void time_head(const float* __restrict__ prefix,
                                                 const float* __restrict__ WtT,
                                                 const float* __restrict__ bt,
                                                 float* __restrict__ out) {
  int lane = threadIdx.x & 63;
  int row = blockIdx.x * 4 + (threadIdx.x >> 6);
  const float4* pr = reinterpret_cast<const float4*>(prefix + (long)row * HID);
  float acc = -3.4e38f;
  if (lane < NTIMES) {
    float a = 0.f;
#pragma unroll 4
    for (int q = 0; q < HID / 4; ++q) {
      float4 pv = pr[q];
      const float* wrow = WtT + q * 4 * NTIMES;
      a += pv.x * wrow[lane] + pv.y * wrow[NTIMES + lane] +
           pv.z * wrow[2 * NTIMES + lane] + pv.w * wrow[3 * NTIMES + lane];
    }
    acc = a + bt[lane];
  }
  float m = acc;
#pragma unroll
  for (int d = 32; d; d >>= 1) m = fmaxf(m, __shfl_xor(m, d));
  float e = (lane < NTIMES) ? __expf(acc - m) : 0.f;
  float s = e;
#pragma unroll
  for (int d = 32; d; d >>= 1) s += __shfl_xor(s, d);
  if (lane < NTIMES) out[89473024 + row * NTIMES + lane] = acc - m - __logf(s);
}

extern "C" void kernel_launch(void* const* d_in, const int* in_sizes, int n_in,
                              void* d_out, int out_size, void* d_ws, size_t ws_size,
                              hipStream_t stream) {
  const float* prefix = (const float*)d_in[0];  // [128,32,1024]
  const float* emb    = (const float*)d_in[1];  // [21844,256]
  const float* Wk     = (const float*)d_in[2];  // [1024,256]
  const float* Wt     = (const float*)d_in[4];  // [48,1024]
  const float* bt     = (const float*)d_in[5];  // [48]
  float* out = (float*)d_out;
  char* ws = (char*)d_ws;

  // workspace layout (16B aligned)
  unsigned short* P2    = (unsigned short*)(ws + 0);          // 4096*256 bf16
  unsigned short* Eb    = (unsigned short*)(ws + 2097152);    // 21844*256 bf16
  unsigned short* WkT   = (unsigned short*)(ws + 13281280);   // 256*1024 bf16
  unsigned short* Pb16  = (unsigned short*)(ws + 13805568);   // 4096*1024 bf16
  float*          WtT   = (float*)(ws + 22194176);            // 1024*48 f32
  float*          S     = (float*)(ws + 22390784);            // 7*4096 f32
  unsigned short* stash = (unsigned short*)(ws + 22505472);   // 89473024 bf16 = 178,946,048 B
  const size_t WS_NEED_STASH = 22505472UL + 178946048UL;      // ~201.5 MB

  bool big = ws_size >= WS_NEED_STASH;

  prep<<<10801, 256, 0, stream>>>(prefix, emb, Wk, Wt, Pb16, Eb, WkT, WtT, S);

  p2_mfma<<<dim3(4, 64), 256, 0, stream>>>(Pb16, WkT, P2);

  if (big) {
    gemm_stash<1><<<dim3(32, 171), 256, 0, stream>>>(P2, Eb, stash, out, S);
    sub_write<1><<<43688, 256, 0, stream>>>(stash, S, out);
  } else {
    gemm_stash<0><<<dim3(32, 171), 256, 0, stream>>>(P2, Eb, stash, out, S);
    sub_write<0><<<43688, 256, 0, stream>>>(stash, S, out);
  }

  time_head<<<1024, 256, 0, stream>>>(prefix, WtT, bt, out);
}